// Round 6
// baseline (1565.012 us; speedup 1.0000x reference)
//
#include <hip/hip_runtime.h>
#include <hip/hip_bf16.h>

typedef unsigned short ushort_t;
using bf16x8 = __attribute__((ext_vector_type(8))) __bf16;
using f32x4  = __attribute__((ext_vector_type(4))) float;
using int2e  = __attribute__((ext_vector_type(2))) int;
using int4e  = __attribute__((ext_vector_type(4))) int;
using us4e   = __attribute__((ext_vector_type(4))) unsigned short;

#define NDIM 256
#define BINB 128   // coarse buckets for two-phase scatter
#define PLACE_G 2  // blocks per bucket in phase B

__device__ __forceinline__ float bf2f(ushort_t u) {
    union { unsigned int i; float f; } x; x.i = ((unsigned int)u) << 16; return x.f;
}
// round-to-nearest-even f32 -> bf16
__device__ __forceinline__ ushort_t f2bf(float f) {
    unsigned int u = __float_as_uint(f);
    unsigned int r = (u + 0x7FFFu + ((u >> 16) & 1u)) >> 16;
    return (ushort_t)r;
}
__device__ __forceinline__ float ldf(const void* p, int i, int isbf) {
    return isbf ? bf2f(((const ushort_t*)p)[i]) : ((const float*)p)[i];
}
__device__ __forceinline__ int get_idx(const void* arr, int i, int is64) {
    if (is64) return (int)((const long long*)arr)[i];
    return ((const int*)arr)[i];
}

// ---- probe m's words: bf16 data has low-u16 bf16-exponent concentrated ----
__global__ void k_probe(const unsigned int* __restrict__ w, int* __restrict__ flag) {
    __shared__ int cnt_in;
    if (threadIdx.x == 0) cnt_in = 0;
    __syncthreads();
    int local = 0;
    for (int i = threadIdx.x; i < 4096; i += blockDim.x) {
        unsigned int e = (w[i] >> 7) & 0xFFu;
        if (e >= 110u && e <= 135u) local++;
    }
    atomicAdd(&cnt_in, local);
    __syncthreads();
    if (threadIdx.x == 0) *flag = (cnt_in >= 2048) ? 1 : 0;
}

// ---- probe index width ----
__global__ void k_detect(const unsigned int* __restrict__ rows_w, int nnz, int* __restrict__ flag) {
    __shared__ int nz;
    if (threadIdx.x == 0) nz = 0;
    __syncthreads();
    int samples = min(nnz / 2, 4096);
    for (int i = threadIdx.x; i < samples; i += blockDim.x) {
        if (rows_w[2 * i + 1] != 0u) atomicAdd(&nz, 1);
    }
    __syncthreads();
    if (threadIdx.x == 0) *flag = (nz == 0) ? 1 : 0;
}

// ---- m -> Hb (canonical bf16) ----
__global__ void k_cvt_m(const void* __restrict__ src, ushort_t* __restrict__ dst, int n,
                        const int* __restrict__ flag) {
    int i = blockIdx.x * blockDim.x + threadIdx.x;
    if (i >= n) return;
    int isbf = *flag;
    dst[i] = isbf ? ((const ushort_t*)src)[i] : f2bf(((const float*)src)[i]);
}

// ---- combined bias bn+bs -> f32 ----
__global__ void k_bias(const void* __restrict__ bn, const void* __restrict__ bs,
                       float* __restrict__ bc, int n, const int* __restrict__ flag) {
    int i = blockIdx.x * blockDim.x + threadIdx.x;
    if (i >= n) return;
    int isbf = *flag;
    bc[i] = ldf(bn, i, isbf) + ldf(bs, i, isbf);
}

// ---- weight pack into MFMA fragment order, split hi/lo bf16 ----
// Bpack layout (ushorts): [hop][kstep 0..15][p 0..31][lane 0..63][j 0..7]
//   p = ntile*2 + hilo ; frag = 512 ush (1KB) ; per-kstep chunk = 16384 ush (32KB)
__global__ void k_wpack(const void* __restrict__ Wn, const void* __restrict__ Ws,
                        ushort_t* __restrict__ bpack, int total, const int* __restrict__ flag) {
    int t = blockIdx.x * blockDim.x + threadIdx.x;
    if (t >= total) return;
    int isbf  = *flag;
    int j     = t & 7;
    int lane  = (t >> 3) & 63;
    int ntile = (t >> 9) & 15;
    int kstep = (t >> 13) & 15;
    int hop   = t >> 17;
    int k = (kstep << 5) + ((lane >> 4) << 3) + j;   // 0..511 activation k
    int n = (ntile << 4) + (lane & 15);              // 0..255 output col
    int kk = k & 255;
    float w = (k < 256) ? ldf(Wn, hop * 65536 + n * 256 + kk, isbf)
                        : ldf(Ws, hop * 65536 + n * 256 + kk, isbf);
    ushort_t hi = f2bf(w);
    float lo = w - bf2f(hi);
    int base = ((((hop << 4) + kstep) << 5) + (ntile << 1)) * 512 + (lane << 3) + j;
    bpack[base]       = hi;
    bpack[base + 512] = f2bf(lo);
}

// ---- CSR build ----
__global__ void k_hist(const void* __restrict__ rows, int* __restrict__ cnt, int nnz,
                       const int* __restrict__ flag) {
    int is64 = *flag;
    int i = blockIdx.x * blockDim.x + threadIdx.x;
    if (i < nnz) atomicAdd(&cnt[get_idx(rows, i, is64)], 1);
}

__global__ void k_chunksum(const int* __restrict__ cnt, int* __restrict__ csum, int n) {
    __shared__ int s[256];
    int i = blockIdx.x * 256 + threadIdx.x;
    int v = (i < n) ? cnt[i] : 0;
    s[threadIdx.x] = v;
    __syncthreads();
    for (int off = 128; off > 0; off >>= 1) {
        if (threadIdx.x < off) s[threadIdx.x] += s[threadIdx.x + off];
        __syncthreads();
    }
    if (threadIdx.x == 0) csum[blockIdx.x] = s[0];
}

__global__ void k_scanchunks(const int* __restrict__ csum, int* __restrict__ coff, int nchunks) {
    __shared__ int a[512], b[512];
    int t = threadIdx.x;
    int v = (t < nchunks) ? csum[t] : 0;
    a[t] = v;
    __syncthreads();
    int* src = a; int* dst = b;
    for (int off = 1; off < 512; off <<= 1) {
        dst[t] = src[t] + ((t >= off) ? src[t - off] : 0);
        __syncthreads();
        int* tmp = src; src = dst; dst = tmp;
    }
    if (t < nchunks) coff[t] = src[t] - v;   // exclusive
}

__global__ void k_scanwrite(const int* __restrict__ cnt, const int* __restrict__ coff,
                            int* __restrict__ row_start, int* __restrict__ row_cur,
                            int n, int nnz) {
    __shared__ int a[256], b[256];
    int t = threadIdx.x;
    int i = blockIdx.x * 256 + t;
    int v = (i < n) ? cnt[i] : 0;
    a[t] = v;
    __syncthreads();
    int* src = a; int* dst = b;
    for (int off = 1; off < 256; off <<= 1) {
        dst[t] = src[t] + ((t >= off) ? src[t - off] : 0);
        __syncthreads();
        int* tmp = src; src = dst; dst = tmp;
    }
    int excl = src[t] - v + coff[blockIdx.x];
    if (i < n) { row_start[i] = excl; row_cur[i] = excl; }
    if (i == n) row_start[n] = nnz;
}

// ---- bucket init ----
__global__ void k_binit(const int* __restrict__ row_start, int* __restrict__ bucket_cur,
                        int* __restrict__ bstart, int n, int sh) {
    int b = threadIdx.x;
    if (b <= BINB) {
        int idx = b << sh;
        if (idx > n) idx = n;
        int rs = row_start[idx];
        bstart[b] = rs;
        if (b < BINB) bucket_cur[b] = rs;
    }
}

// ---- phase A: bin edges into BINB coarse buckets ----
__global__ __launch_bounds__(256) void k_bin(
        const void* __restrict__ rows, const void* __restrict__ cols,
        const void* __restrict__ vals, int* __restrict__ bucket_cur,
        int4e* __restrict__ tmp, int nnz, int sh,
        const int* __restrict__ iflag, const int* __restrict__ fflag) {
    __shared__ int cntL[BINB];
    __shared__ int curL[BINB];
    int is64 = *iflag, isbf = *fflag;
    int tid = threadIdx.x;
    int base = blockIdx.x * 4096;
    if (tid < BINB) cntL[tid] = 0;
    __syncthreads();
    int r[16], b[16];
    #pragma unroll
    for (int j = 0; j < 16; ++j) {
        int idx = base + (j << 8) + tid;
        if (idx < nnz) {
            r[j] = get_idx(rows, idx, is64);
            b[j] = r[j] >> sh;
            atomicAdd(&cntL[b[j]], 1);
        } else b[j] = -1;
    }
    __syncthreads();
    if (tid < BINB) curL[tid] = atomicAdd(&bucket_cur[tid], cntL[tid]);
    __syncthreads();
    #pragma unroll
    for (int j = 0; j < 16; ++j) {
        int idx = base + (j << 8) + tid;
        if (idx < nnz) {
            int c = get_idx(cols, idx, is64);
            float v = ldf(vals, idx, isbf);
            int p = atomicAdd(&curL[b[j]], 1);
            int4e ed; ed[0] = r[j]; ed[1] = c; ed[2] = __float_as_int(v); ed[3] = 0;
            __builtin_nontemporal_store(ed, &tmp[p]);   // single-use stream: keep out of L2
        }
    }
}

// ---- phase B: exact CSR placement within one bucket's L2-resident window ----
__global__ __launch_bounds__(256) void k_place(
        const int4e* __restrict__ tmp, const int* __restrict__ bstart,
        int* __restrict__ row_cur, int2e* __restrict__ edata) {
    int blk = blockIdx.x;
    int xcd = blk & 7;
    int q   = blk >> 3;
    int g   = q & (PLACE_G - 1);
    int bq  = q >> 1;                 // log2(PLACE_G) = 1
    int b   = (bq << 3) | xcd;
    int e0 = bstart[b], e1 = bstart[b + 1];
    int len = e1 - e0;
    if (len <= 0) return;
    int sub = (len + PLACE_G - 1) / PLACE_G;
    int es = e0 + g * sub;
    int ee = min(es + sub, e1);
    for (int e = es + threadIdx.x; e < ee; e += 256) {
        int4e ed = __builtin_nontemporal_load(&tmp[e]);
        int p = atomicAdd(&row_cur[ed[0]], 1);
        int2e o; o[0] = ed[1]; o[1] = ed[2];
        edata[p] = o;
    }
}

// ---- SpMM: one wave per row, fp32 accumulate, bf16 in/out ----
// 4 independent gather chains in flight (two int4e edge loads + 4 acc sets)
// to convert miss latency into bandwidth; nt hints on streaming edata/Hn.
__global__ void k_spmm(const ushort_t* __restrict__ hb, const int* __restrict__ row_start,
                       const int2e* __restrict__ edata, ushort_t* __restrict__ hn, int n) {
    int wid = (blockIdx.x * blockDim.x + threadIdx.x) >> 6;
    if (wid >= n) return;
    wid = __builtin_amdgcn_readfirstlane(wid);
    int lane = threadIdx.x & 63;
    int e0 = row_start[wid];
    int e1 = row_start[wid + 1];
    float a0 = 0.f, a1 = 0.f, a2 = 0.f, a3 = 0.f;
    float b0 = 0.f, b1 = 0.f, b2 = 0.f, b3 = 0.f;
    float c0 = 0.f, c1 = 0.f, c2 = 0.f, c3 = 0.f;
    float d0 = 0.f, d1 = 0.f, d2 = 0.f, d3 = 0.f;
    int off = lane * 4;
    int e = e0;
    if ((e & 1) && e < e1) {           // align to 16B edata pairs
        int2e ed = __builtin_nontemporal_load(&edata[e]);
        float v = __int_as_float(ed[1]);
        ushort4 h = *reinterpret_cast<const ushort4*>(hb + (((long)ed[0]) << 8) + off);
        a0 += bf2f(h.x) * v; a1 += bf2f(h.y) * v;
        a2 += bf2f(h.z) * v; a3 += bf2f(h.w) * v;
        ++e;
    }
    for (; e + 3 < e1; e += 4) {       // 4 independent gather+acc chains
        int4e p0 = __builtin_nontemporal_load(reinterpret_cast<const int4e*>(&edata[e]));
        int4e p1 = __builtin_nontemporal_load(reinterpret_cast<const int4e*>(&edata[e + 2]));
        float v0 = __int_as_float(p0[1]);
        float v1 = __int_as_float(p0[3]);
        float v2 = __int_as_float(p1[1]);
        float v3 = __int_as_float(p1[3]);
        ushort4 h0 = *reinterpret_cast<const ushort4*>(hb + (((long)p0[0]) << 8) + off);
        ushort4 h1 = *reinterpret_cast<const ushort4*>(hb + (((long)p0[2]) << 8) + off);
        ushort4 h2 = *reinterpret_cast<const ushort4*>(hb + (((long)p1[0]) << 8) + off);
        ushort4 h3 = *reinterpret_cast<const ushort4*>(hb + (((long)p1[2]) << 8) + off);
        a0 += bf2f(h0.x) * v0; a1 += bf2f(h0.y) * v0;
        a2 += bf2f(h0.z) * v0; a3 += bf2f(h0.w) * v0;
        b0 += bf2f(h1.x) * v1; b1 += bf2f(h1.y) * v1;
        b2 += bf2f(h1.z) * v1; b3 += bf2f(h1.w) * v1;
        c0 += bf2f(h2.x) * v2; c1 += bf2f(h2.y) * v2;
        c2 += bf2f(h2.z) * v2; c3 += bf2f(h2.w) * v2;
        d0 += bf2f(h3.x) * v3; d1 += bf2f(h3.y) * v3;
        d2 += bf2f(h3.z) * v3; d3 += bf2f(h3.w) * v3;
    }
    for (; e + 1 < e1; e += 2) {
        int4e p0 = __builtin_nontemporal_load(reinterpret_cast<const int4e*>(&edata[e]));
        float v0 = __int_as_float(p0[1]);
        float v1 = __int_as_float(p0[3]);
        ushort4 h0 = *reinterpret_cast<const ushort4*>(hb + (((long)p0[0]) << 8) + off);
        ushort4 h1 = *reinterpret_cast<const ushort4*>(hb + (((long)p0[2]) << 8) + off);
        a0 += bf2f(h0.x) * v0; a1 += bf2f(h0.y) * v0;
        a2 += bf2f(h0.z) * v0; a3 += bf2f(h0.w) * v0;
        b0 += bf2f(h1.x) * v1; b1 += bf2f(h1.y) * v1;
        b2 += bf2f(h1.z) * v1; b3 += bf2f(h1.w) * v1;
    }
    if (e < e1) {
        int2e ed = __builtin_nontemporal_load(&edata[e]);
        float v = __int_as_float(ed[1]);
        ushort4 h = *reinterpret_cast<const ushort4*>(hb + (((long)ed[0]) << 8) + off);
        a0 += bf2f(h.x) * v; a1 += bf2f(h.y) * v;
        a2 += bf2f(h.z) * v; a3 += bf2f(h.w) * v;
    }
    a0 += b0 + c0 + d0; a1 += b1 + c1 + d1;
    a2 += b2 + c2 + d2; a3 += b3 + c3 + d3;
    us4e o;
    o[0] = f2bf(a0); o[1] = f2bf(a1); o[2] = f2bf(a2); o[3] = f2bf(a3);
    __builtin_nontemporal_store(o, reinterpret_cast<us4e*>(hn + (((long)wid) << 8) + off));
}

// ---- stage one 32KB Bpack k-chunk into LDS via async global->LDS, 16B/lane ----
__device__ __forceinline__ void stage32k(const ushort_t* __restrict__ src, ushort_t* dstlds, int tid) {
    const char* s = (const char*)src;
    char* d = (char*)dstlds;
    #pragma unroll
    for (int i = 0; i < 8; ++i) {
        int off = i * 4096 + tid * 16;
        __builtin_amdgcn_global_load_lds(
            (const __attribute__((address_space(1))) unsigned int*)(s + off),
            (__attribute__((address_space(3))) unsigned int*)(d + off),
            16, 0, 0);
    }
}

__device__ __forceinline__ void loadA4(bf16x8* af, const ushort_t* __restrict__ asrc,
                                       long rowbase, int lr, int kcol) {
    #pragma unroll
    for (int mf = 0; mf < 4; ++mf) {
        long row = rowbase + mf * 16 + lr;
        af[mf] = *(const bf16x8*)(asrc + (row << 8) + kcol);
    }
}

// ---- MFMA GEMM: out[r][n] = act( sum_k Hn[r][k]*WtN[k][n] + Hb[r][k]*WtS[k][n] + bc[n] )
// Single barrier per K-step; stage(ks+1) + A-prefetch issued AFTER the barrier so
// their latency hides under compute(ks).
__global__ __launch_bounds__(256, 2) void k_gemm_mfma(
        const ushort_t* __restrict__ hn, const ushort_t* __restrict__ hb,
        const ushort_t* __restrict__ bpack, const float* __restrict__ bc,
        void* __restrict__ dst, int applyElu, int writeF32, int nvalid) {
    __shared__ __align__(16) ushort_t lds[2][16384];   // 2 x 32KB
    int tid  = threadIdx.x;
    int wave = tid >> 6, lane = tid & 63;
    int wm = wave >> 1, wn = wave & 1;
    long rowbase = blockIdx.x * 128 + wm * 64;
    int lr = lane & 15;            // A-row / B-col / D-col within fragment
    int lk = (lane >> 4) << 3;     // k sub-offset 0,8,16,24

    f32x4 acc[4][8];
    #pragma unroll
    for (int mf = 0; mf < 4; ++mf)
        #pragma unroll
        for (int nf = 0; nf < 8; ++nf) acc[mf][nf] = (f32x4){0.f, 0.f, 0.f, 0.f};

    bf16x8 afA[4], afB[4];
    stage32k(bpack, &lds[0][0], tid);
    loadA4(afA, hn, rowbase, lr, lk);   // ks=0: asrc=hn, kcol=lk

    #pragma unroll 2
    for (int ks = 0; ks < 16; ++ks) {
        __syncthreads();   // drains stage(ks) + A(ks) issued one iter ago -> ready
        bf16x8* afc = (ks & 1) ? afB : afA;
        bf16x8* afn = (ks & 1) ? afA : afB;
        if (ks < 15) {
            stage32k(bpack + (ks + 1) * 16384, &lds[(ks + 1) & 1][0], tid);
            const ushort_t* asrc = ((ks + 1) < 8) ? hn : hb;
            int kcol = (((ks + 1) & 7) << 5) + lk;
            loadA4(afn, asrc, rowbase, lr, kcol);
        }
        const ushort_t* bb = &lds[ks & 1][0];
        #pragma unroll
        for (int nf = 0; nf < 8; ++nf) {
            const ushort_t* fp = bb + ((((wn << 3) + nf) << 1) << 9) + (lane << 3);
            bf16x8 bhi = *(const bf16x8*)(fp);
            bf16x8 blo = *(const bf16x8*)(fp + 512);
            #pragma unroll
            for (int mf = 0; mf < 4; ++mf) {
                acc[mf][nf] = __builtin_amdgcn_mfma_f32_16x16x32_bf16(afc[mf], bhi, acc[mf][nf], 0, 0, 0);
                acc[mf][nf] = __builtin_amdgcn_mfma_f32_16x16x32_bf16(afc[mf], blo, acc[mf][nf], 0, 0, 0);
            }
        }
    }

    // epilogue: D frag layout col=lane&15, row=(lane>>4)*4+reg (m89-verified)
    int colb = wn << 7;
    float bcv[8];
    #pragma unroll
    for (int nf = 0; nf < 8; ++nf) bcv[nf] = bc[colb + (nf << 4) + lr];
    int rsub = (lane >> 4) << 2;
    #pragma unroll
    for (int mf = 0; mf < 4; ++mf) {
        #pragma unroll
        for (int r = 0; r < 4; ++r) {
            long row = rowbase + mf * 16 + rsub + r;
            if (row < nvalid) {
                #pragma unroll
                for (int nf = 0; nf < 8; ++nf) {
                    float v = acc[mf][nf][r] + bcv[nf];
                    if (applyElu) v = (v > 0.f) ? v : expm1f(v);
                    int col = colb + (nf << 4) + lr;
                    if (writeF32) ((float*)dst)[(row << 8) + col] = v;
                    else          ((ushort_t*)dst)[(row << 8) + col] = f2bf(v);
                }
            }
        }
    }
}

extern "C" void kernel_launch(void* const* d_in, const int* in_sizes, int n_in,
                              void* d_out, int out_size, void* d_ws, size_t ws_size,
                              hipStream_t stream) {
    const void* m    = d_in[0];
    const void* vals = d_in[1];
    const void* Wn   = d_in[2];
    const void* bn   = d_in[3];
    const void* Ws   = d_in[4];
    const void* bs   = d_in[5];
    const void* rows = d_in[6];
    const void* cols = d_in[7];

    const int N    = in_sizes[0] / NDIM;      // 100000
    const int nnz  = in_sizes[1];             // 3200000
    const int hops = in_sizes[3] / NDIM;      // 3
    const size_t mpad = ((size_t)N + 127) & ~(size_t)127;   // 128-row tiles

    char* p = (char*)d_ws;
    ushort_t* Hb    = (ushort_t*)p; p += mpad * NDIM * 2;
    ushort_t* Hn    = (ushort_t*)p; p += mpad * NDIM * 2;
    ushort_t* Bpack = (ushort_t*)p; p += (size_t)hops * 262144 * 2;  // 512KB/hop
    float* Bc       = (float*)p; p += (size_t)hops * 256 * 4;
    int* cnt        = (int*)p; p += ((size_t)N + 256) * 4;
    int* row_start  = (int*)p; p += ((size_t)N + 256) * 4;
    int* row_cur    = (int*)p; p += ((size_t)N + 256) * 4;
    int* csum       = (int*)p; p += 512 * 4;
    int* coff       = (int*)p; p += 512 * 4;
    int* bucket_cur = (int*)p; p += 256 * 4;
    int* bstart     = (int*)p; p += 256 * 4;
    int* iflag      = (int*)p; p += 64;
    int* fflag      = (int*)p; p += 64;
    p = (char*)(((uintptr_t)p + 15) & ~(uintptr_t)15);
    int2e* edata = (int2e*)p; p += (size_t)nnz * 8;

    // int4 temp for binned edges: alias Hn (dead until first SpMM) when it fits
    int4e* tmp;
    if ((size_t)nnz * 16 <= mpad * NDIM * 2) {
        tmp = (int4e*)Hn;
    } else {
        p = (char*)(((uintptr_t)p + 15) & ~(uintptr_t)15);
        tmp = (int4e*)p; p += (size_t)nnz * 16;
    }

    (void)hipMemsetAsync(cnt, 0, (size_t)(N + 1) * sizeof(int), stream);
    if (mpad > (size_t)N) {
        (void)hipMemsetAsync(Hb + (size_t)N * NDIM, 0, (mpad - N) * NDIM * 2, stream);
    }

    k_probe<<<1, 256, 0, stream>>>((const unsigned int*)m, fflag);
    k_detect<<<1, 256, 0, stream>>>((const unsigned int*)rows, nnz, iflag);

    int nm = N * NDIM;
    k_cvt_m<<<(nm + 255) / 256, 256, 0, stream>>>(m, Hb, nm, fflag);

    int nb = hops * 256;
    k_bias<<<(nb + 255) / 256, 256, 0, stream>>>(bn, bs, Bc, nb, fflag);

    int wtotal = hops << 17;
    k_wpack<<<(wtotal + 255) / 256, 256, 0, stream>>>(Wn, Ws, Bpack, wtotal, fflag);

    k_hist<<<(nnz + 255) / 256, 256, 0, stream>>>(rows, cnt, nnz, iflag);

    int nchunks = (N + 255) / 256;
    k_chunksum<<<nchunks, 256, 0, stream>>>(cnt, csum, N);
    k_scanchunks<<<1, 512, 0, stream>>>(csum, coff, nchunks);
    k_scanwrite<<<nchunks, 256, 0, stream>>>(cnt, coff, row_start, row_cur, N, nnz);

    // bucket shift: smallest sh with (N-1)>>sh < BINB
    int sh = 0;
    while (((N - 1) >> sh) >= BINB) sh++;

    k_binit<<<1, 256, 0, stream>>>(row_start, bucket_cur, bstart, N, sh);
    k_bin<<<(nnz + 4095) / 4096, 256, 0, stream>>>(rows, cols, vals, bucket_cur, tmp, nnz, sh, iflag, fflag);
    k_place<<<(BINB / 8) * PLACE_G * 8, 256, 0, stream>>>(tmp, bstart, row_cur, edata);

    if (mpad > (size_t)N) {
        (void)hipMemsetAsync(Hn + (size_t)N * NDIM, 0, (mpad - N) * NDIM * 2, stream);
    }

    int spmm_blocks = (N + 3) / 4;
    int gemm_blocks = (int)(mpad / 128);

    for (int hop = 0; hop < hops; ++hop) {
        k_spmm<<<spmm_blocks, 256, 0, stream>>>(Hb, row_start, edata, Hn, N);
        int last = (hop == hops - 1);
        void* dst = last ? d_out : (void*)Hb;
        k_gemm_mfma<<<gemm_blocks, 256, 0, stream>>>(
            Hn, Hb,
            Bpack + (size_t)hop * 262144,
            Bc + (size_t)hop * 256,
            dst, last ? 0 : 1, last ? 1 : 0, N);
    }
}

// Round 7
// 1448.881 us; speedup vs baseline: 1.0802x; 1.0802x over previous
//
#include <hip/hip_runtime.h>
#include <hip/hip_bf16.h>

typedef unsigned short ushort_t;
using bf16x8 = __attribute__((ext_vector_type(8))) __bf16;
using f32x4  = __attribute__((ext_vector_type(4))) float;
using int2e  = __attribute__((ext_vector_type(2))) int;
using int4e  = __attribute__((ext_vector_type(4))) int;
using us4e   = __attribute__((ext_vector_type(4))) unsigned short;

#define NDIM 256
#define BINB 128   // coarse buckets for two-phase scatter
#define PLACE_G 2  // blocks per bucket in phase B

__device__ __forceinline__ float bf2f(ushort_t u) {
    union { unsigned int i; float f; } x; x.i = ((unsigned int)u) << 16; return x.f;
}
// round-to-nearest-even f32 -> bf16
__device__ __forceinline__ ushort_t f2bf(float f) {
    unsigned int u = __float_as_uint(f);
    unsigned int r = (u + 0x7FFFu + ((u >> 16) & 1u)) >> 16;
    return (ushort_t)r;
}
__device__ __forceinline__ float ldf(const void* p, int i, int isbf) {
    return isbf ? bf2f(((const ushort_t*)p)[i]) : ((const float*)p)[i];
}
__device__ __forceinline__ int get_idx(const void* arr, int i, int is64) {
    if (is64) return (int)((const long long*)arr)[i];
    return ((const int*)arr)[i];
}

// ---- probe m's words: bf16 data has low-u16 bf16-exponent concentrated ----
__global__ void k_probe(const unsigned int* __restrict__ w, int* __restrict__ flag) {
    __shared__ int cnt_in;
    if (threadIdx.x == 0) cnt_in = 0;
    __syncthreads();
    int local = 0;
    for (int i = threadIdx.x; i < 4096; i += blockDim.x) {
        unsigned int e = (w[i] >> 7) & 0xFFu;
        if (e >= 110u && e <= 135u) local++;
    }
    atomicAdd(&cnt_in, local);
    __syncthreads();
    if (threadIdx.x == 0) *flag = (cnt_in >= 2048) ? 1 : 0;
}

// ---- probe index width ----
__global__ void k_detect(const unsigned int* __restrict__ rows_w, int nnz, int* __restrict__ flag) {
    __shared__ int nz;
    if (threadIdx.x == 0) nz = 0;
    __syncthreads();
    int samples = min(nnz / 2, 4096);
    for (int i = threadIdx.x; i < samples; i += blockDim.x) {
        if (rows_w[2 * i + 1] != 0u) atomicAdd(&nz, 1);
    }
    __syncthreads();
    if (threadIdx.x == 0) *flag = (nz == 0) ? 1 : 0;
}

// ---- m -> Hb (canonical bf16), 32B per thread (G13: vectorize memory-bound passes) ----
__global__ void k_cvt_m8(const void* __restrict__ src, ushort_t* __restrict__ dst, int n8,
                         const int* __restrict__ flag) {
    int i = blockIdx.x * blockDim.x + threadIdx.x;
    if (i >= n8) return;
    int isbf = *flag;
    us4e* d = reinterpret_cast<us4e*>(dst);
    if (isbf) {
        const us4e* s = reinterpret_cast<const us4e*>(src);
        d[2 * i]     = s[2 * i];
        d[2 * i + 1] = s[2 * i + 1];
    } else {
        const f32x4* s = reinterpret_cast<const f32x4*>(src);
        f32x4 a = s[2 * i];
        f32x4 b = s[2 * i + 1];
        us4e o0, o1;
        o0[0] = f2bf(a[0]); o0[1] = f2bf(a[1]); o0[2] = f2bf(a[2]); o0[3] = f2bf(a[3]);
        o1[0] = f2bf(b[0]); o1[1] = f2bf(b[1]); o1[2] = f2bf(b[2]); o1[3] = f2bf(b[3]);
        d[2 * i]     = o0;
        d[2 * i + 1] = o1;
    }
}

// ---- combined bias bn+bs -> f32 ----
__global__ void k_bias(const void* __restrict__ bn, const void* __restrict__ bs,
                       float* __restrict__ bc, int n, const int* __restrict__ flag) {
    int i = blockIdx.x * blockDim.x + threadIdx.x;
    if (i >= n) return;
    int isbf = *flag;
    bc[i] = ldf(bn, i, isbf) + ldf(bs, i, isbf);
}

// ---- weight pack into MFMA fragment order, split hi/lo bf16 ----
// Bpack layout (ushorts): [hop][kstep 0..15][p 0..31][lane 0..63][j 0..7]
//   p = ntile*2 + hilo ; frag = 512 ush (1KB) ; per-kstep chunk = 16384 ush (32KB)
__global__ void k_wpack(const void* __restrict__ Wn, const void* __restrict__ Ws,
                        ushort_t* __restrict__ bpack, int total, const int* __restrict__ flag) {
    int t = blockIdx.x * blockDim.x + threadIdx.x;
    if (t >= total) return;
    int isbf  = *flag;
    int j     = t & 7;
    int lane  = (t >> 3) & 63;
    int ntile = (t >> 9) & 15;
    int kstep = (t >> 13) & 15;
    int hop   = t >> 17;
    int k = (kstep << 5) + ((lane >> 4) << 3) + j;   // 0..511 activation k
    int n = (ntile << 4) + (lane & 15);              // 0..255 output col
    int kk = k & 255;
    float w = (k < 256) ? ldf(Wn, hop * 65536 + n * 256 + kk, isbf)
                        : ldf(Ws, hop * 65536 + n * 256 + kk, isbf);
    ushort_t hi = f2bf(w);
    float lo = w - bf2f(hi);
    int base = ((((hop << 4) + kstep) << 5) + (ntile << 1)) * 512 + (lane << 3) + j;
    bpack[base]       = hi;
    bpack[base + 512] = f2bf(lo);
}

// ---- CSR build ----
__global__ void k_hist(const void* __restrict__ rows, int* __restrict__ cnt, int nnz,
                       const int* __restrict__ flag) {
    int is64 = *flag;
    int i = blockIdx.x * blockDim.x + threadIdx.x;
    if (i < nnz) atomicAdd(&cnt[get_idx(rows, i, is64)], 1);
}

__global__ void k_chunksum(const int* __restrict__ cnt, int* __restrict__ csum, int n) {
    __shared__ int s[256];
    int i = blockIdx.x * 256 + threadIdx.x;
    int v = (i < n) ? cnt[i] : 0;
    s[threadIdx.x] = v;
    __syncthreads();
    for (int off = 128; off > 0; off >>= 1) {
        if (threadIdx.x < off) s[threadIdx.x] += s[threadIdx.x + off];
        __syncthreads();
    }
    if (threadIdx.x == 0) csum[blockIdx.x] = s[0];
}

__global__ void k_scanchunks(const int* __restrict__ csum, int* __restrict__ coff, int nchunks) {
    __shared__ int a[512], b[512];
    int t = threadIdx.x;
    int v = (t < nchunks) ? csum[t] : 0;
    a[t] = v;
    __syncthreads();
    int* src = a; int* dst = b;
    for (int off = 1; off < 512; off <<= 1) {
        dst[t] = src[t] + ((t >= off) ? src[t - off] : 0);
        __syncthreads();
        int* tmp = src; src = dst; dst = tmp;
    }
    if (t < nchunks) coff[t] = src[t] - v;   // exclusive
}

__global__ void k_scanwrite(const int* __restrict__ cnt, const int* __restrict__ coff,
                            int* __restrict__ row_start, int* __restrict__ row_cur,
                            int n, int nnz) {
    __shared__ int a[256], b[256];
    int t = threadIdx.x;
    int i = blockIdx.x * 256 + t;
    int v = (i < n) ? cnt[i] : 0;
    a[t] = v;
    __syncthreads();
    int* src = a; int* dst = b;
    for (int off = 1; off < 256; off <<= 1) {
        dst[t] = src[t] + ((t >= off) ? src[t - off] : 0);
        __syncthreads();
        int* tmp = src; src = dst; dst = tmp;
    }
    int excl = src[t] - v + coff[blockIdx.x];
    if (i < n) { row_start[i] = excl; row_cur[i] = excl; }
    if (i == n) row_start[n] = nnz;
}

// ---- bucket init ----
__global__ void k_binit(const int* __restrict__ row_start, int* __restrict__ bucket_cur,
                        int* __restrict__ bstart, int n, int sh) {
    int b = threadIdx.x;
    if (b <= BINB) {
        int idx = b << sh;
        if (idx > n) idx = n;
        int rs = row_start[idx];
        bstart[b] = rs;
        if (b < BINB) bucket_cur[b] = rs;
    }
}

// ---- phase A: bin edges into BINB coarse buckets ----
__global__ __launch_bounds__(256) void k_bin(
        const void* __restrict__ rows, const void* __restrict__ cols,
        const void* __restrict__ vals, int* __restrict__ bucket_cur,
        int4e* __restrict__ tmp, int nnz, int sh,
        const int* __restrict__ iflag, const int* __restrict__ fflag) {
    __shared__ int cntL[BINB];
    __shared__ int curL[BINB];
    int is64 = *iflag, isbf = *fflag;
    int tid = threadIdx.x;
    int base = blockIdx.x * 4096;
    if (tid < BINB) cntL[tid] = 0;
    __syncthreads();
    int r[16], b[16];
    #pragma unroll
    for (int j = 0; j < 16; ++j) {
        int idx = base + (j << 8) + tid;
        if (idx < nnz) {
            r[j] = get_idx(rows, idx, is64);
            b[j] = r[j] >> sh;
            atomicAdd(&cntL[b[j]], 1);
        } else b[j] = -1;
    }
    __syncthreads();
    if (tid < BINB) curL[tid] = atomicAdd(&bucket_cur[tid], cntL[tid]);
    __syncthreads();
    #pragma unroll
    for (int j = 0; j < 16; ++j) {
        int idx = base + (j << 8) + tid;
        if (idx < nnz) {
            int c = get_idx(cols, idx, is64);
            float v = ldf(vals, idx, isbf);
            int p = atomicAdd(&curL[b[j]], 1);
            int4e ed; ed[0] = r[j]; ed[1] = c; ed[2] = __float_as_int(v); ed[3] = 0;
            tmp[p] = ed;   // normal store: tmp is re-read immediately by k_place (keep in L2)
        }
    }
}

// ---- phase B: exact CSR placement within one bucket's L2-resident window ----
__global__ __launch_bounds__(256) void k_place(
        const int4e* __restrict__ tmp, const int* __restrict__ bstart,
        int* __restrict__ row_cur, int2e* __restrict__ edata) {
    int blk = blockIdx.x;
    int xcd = blk & 7;
    int q   = blk >> 3;
    int g   = q & (PLACE_G - 1);
    int bq  = q >> 1;                 // log2(PLACE_G) = 1
    int b   = (bq << 3) | xcd;
    int e0 = bstart[b], e1 = bstart[b + 1];
    int len = e1 - e0;
    if (len <= 0) return;
    int sub = (len + PLACE_G - 1) / PLACE_G;
    int es = e0 + g * sub;
    int ee = min(es + sub, e1);
    for (int e = es + threadIdx.x; e < ee; e += 256) {
        int4e ed = tmp[e];
        int p = atomicAdd(&row_cur[ed[0]], 1);
        int2e o; o[0] = ed[1]; o[1] = ed[2];
        edata[p] = o;
    }
}

// ---- SpMM: one wave per row, fp32 accumulate, bf16 in/out ----
// BW-bound on the L2-miss path (~3.8 TB/s plateau, FETCH 768 MB): 2 gather
// chains suffice; nt hints keep streaming edata/Hn out of L2 for the Hb gather.
__global__ void k_spmm(const ushort_t* __restrict__ hb, const int* __restrict__ row_start,
                       const int2e* __restrict__ edata, ushort_t* __restrict__ hn, int n) {
    int wid = (blockIdx.x * blockDim.x + threadIdx.x) >> 6;
    if (wid >= n) return;
    wid = __builtin_amdgcn_readfirstlane(wid);
    int lane = threadIdx.x & 63;
    int e0 = row_start[wid];
    int e1 = row_start[wid + 1];
    float a0 = 0.f, a1 = 0.f, a2 = 0.f, a3 = 0.f;
    float c0 = 0.f, c1 = 0.f, c2 = 0.f, c3 = 0.f;
    int off = lane * 4;
    int e = e0;
    if ((e & 1) && e < e1) {           // align to 16B edata pairs
        int2e ed = __builtin_nontemporal_load(&edata[e]);
        float v = __int_as_float(ed[1]);
        ushort4 h = *reinterpret_cast<const ushort4*>(hb + (((long)ed[0]) << 8) + off);
        a0 += bf2f(h.x) * v; a1 += bf2f(h.y) * v;
        a2 += bf2f(h.z) * v; a3 += bf2f(h.w) * v;
        ++e;
    }
    for (; e + 1 < e1; e += 2) {
        int4e p0 = __builtin_nontemporal_load(reinterpret_cast<const int4e*>(&edata[e]));
        float v0 = __int_as_float(p0[1]);
        float v1 = __int_as_float(p0[3]);
        ushort4 h0 = *reinterpret_cast<const ushort4*>(hb + (((long)p0[0]) << 8) + off);
        ushort4 h1 = *reinterpret_cast<const ushort4*>(hb + (((long)p0[2]) << 8) + off);
        a0 += bf2f(h0.x) * v0; a1 += bf2f(h0.y) * v0;
        a2 += bf2f(h0.z) * v0; a3 += bf2f(h0.w) * v0;
        c0 += bf2f(h1.x) * v1; c1 += bf2f(h1.y) * v1;
        c2 += bf2f(h1.z) * v1; c3 += bf2f(h1.w) * v1;
    }
    if (e < e1) {
        int2e ed = __builtin_nontemporal_load(&edata[e]);
        float v = __int_as_float(ed[1]);
        ushort4 h = *reinterpret_cast<const ushort4*>(hb + (((long)ed[0]) << 8) + off);
        a0 += bf2f(h.x) * v; a1 += bf2f(h.y) * v;
        a2 += bf2f(h.z) * v; a3 += bf2f(h.w) * v;
    }
    a0 += c0; a1 += c1; a2 += c2; a3 += c3;
    us4e o;
    o[0] = f2bf(a0); o[1] = f2bf(a1); o[2] = f2bf(a2); o[3] = f2bf(a3);
    __builtin_nontemporal_store(o, reinterpret_cast<us4e*>(hn + (((long)wid) << 8) + off));
}

// ---- stage one 32KB Bpack k-chunk into LDS via async global->LDS, 16B/lane ----
__device__ __forceinline__ void stage32k(const ushort_t* __restrict__ src, ushort_t* dstlds, int tid) {
    const char* s = (const char*)src;
    char* d = (char*)dstlds;
    #pragma unroll
    for (int i = 0; i < 8; ++i) {
        int off = i * 4096 + tid * 16;
        __builtin_amdgcn_global_load_lds(
            (const __attribute__((address_space(1))) unsigned int*)(s + off),
            (__attribute__((address_space(3))) unsigned int*)(d + off),
            16, 0, 0);
    }
}

__device__ __forceinline__ void loadA4(bf16x8* af, const ushort_t* __restrict__ asrc,
                                       long rowbase, int lr, int kcol) {
    #pragma unroll
    for (int mf = 0; mf < 4; ++mf) {
        long row = rowbase + mf * 16 + lr;
        af[mf] = *(const bf16x8*)(asrc + (row << 8) + kcol);
    }
}

// ---- MFMA GEMM: out[r][n] = act( sum_k Hn[r][k]*WtN[k][n] + Hb[r][k]*WtS[k][n] + bc[n] )
// Minimum 2-phase schedule (T3 recipe): single barrier per K-step; stage(ks+1) +
// A-prefetch issued AFTER the barrier so their latency hides under compute(ks).
__global__ __launch_bounds__(256, 2) void k_gemm_mfma(
        const ushort_t* __restrict__ hn, const ushort_t* __restrict__ hb,
        const ushort_t* __restrict__ bpack, const float* __restrict__ bc,
        void* __restrict__ dst, int applyElu, int writeF32, int nvalid) {
    __shared__ __align__(16) ushort_t lds[2][16384];   // 2 x 32KB
    int tid  = threadIdx.x;
    int wave = tid >> 6, lane = tid & 63;
    int wm = wave >> 1, wn = wave & 1;
    long rowbase = blockIdx.x * 128 + wm * 64;
    int lr = lane & 15;            // A-row / B-col / D-col within fragment
    int lk = (lane >> 4) << 3;     // k sub-offset 0,8,16,24

    f32x4 acc[4][8];
    #pragma unroll
    for (int mf = 0; mf < 4; ++mf)
        #pragma unroll
        for (int nf = 0; nf < 8; ++nf) acc[mf][nf] = (f32x4){0.f, 0.f, 0.f, 0.f};

    bf16x8 afA[4], afB[4];
    stage32k(bpack, &lds[0][0], tid);
    loadA4(afA, hn, rowbase, lr, lk);   // ks=0: asrc=hn, kcol=lk

    #pragma unroll 2
    for (int ks = 0; ks < 16; ++ks) {
        __syncthreads();   // drains stage(ks) + A(ks) issued one iter ago -> ready
        bf16x8* afc = (ks & 1) ? afB : afA;
        bf16x8* afn = (ks & 1) ? afA : afB;
        if (ks < 15) {
            stage32k(bpack + (ks + 1) * 16384, &lds[(ks + 1) & 1][0], tid);
            const ushort_t* asrc = ((ks + 1) < 8) ? hn : hb;
            int kcol = (((ks + 1) & 7) << 5) + lk;
            loadA4(afn, asrc, rowbase, lr, kcol);
        }
        const ushort_t* bb = &lds[ks & 1][0];
        #pragma unroll
        for (int nf = 0; nf < 8; ++nf) {
            const ushort_t* fp = bb + ((((wn << 3) + nf) << 1) << 9) + (lane << 3);
            bf16x8 bhi = *(const bf16x8*)(fp);
            bf16x8 blo = *(const bf16x8*)(fp + 512);
            #pragma unroll
            for (int mf = 0; mf < 4; ++mf) {
                acc[mf][nf] = __builtin_amdgcn_mfma_f32_16x16x32_bf16(afc[mf], bhi, acc[mf][nf], 0, 0, 0);
                acc[mf][nf] = __builtin_amdgcn_mfma_f32_16x16x32_bf16(afc[mf], blo, acc[mf][nf], 0, 0, 0);
            }
        }
    }

    // epilogue: D frag layout col=lane&15, row=(lane>>4)*4+reg (m89-verified)
    int colb = wn << 7;
    float bcv[8];
    #pragma unroll
    for (int nf = 0; nf < 8; ++nf) bcv[nf] = bc[colb + (nf << 4) + lr];
    int rsub = (lane >> 4) << 2;
    #pragma unroll
    for (int mf = 0; mf < 4; ++mf) {
        #pragma unroll
        for (int r = 0; r < 4; ++r) {
            long row = rowbase + mf * 16 + rsub + r;
            if (row < nvalid) {
                #pragma unroll
                for (int nf = 0; nf < 8; ++nf) {
                    float v = acc[mf][nf][r] + bcv[nf];
                    if (applyElu) v = (v > 0.f) ? v : expm1f(v);
                    int col = colb + (nf << 4) + lr;
                    if (writeF32) ((float*)dst)[(row << 8) + col] = v;
                    else          ((ushort_t*)dst)[(row << 8) + col] = f2bf(v);
                }
            }
        }
    }
}

extern "C" void kernel_launch(void* const* d_in, const int* in_sizes, int n_in,
                              void* d_out, int out_size, void* d_ws, size_t ws_size,
                              hipStream_t stream) {
    const void* m    = d_in[0];
    const void* vals = d_in[1];
    const void* Wn   = d_in[2];
    const void* bn   = d_in[3];
    const void* Ws   = d_in[4];
    const void* bs   = d_in[5];
    const void* rows = d_in[6];
    const void* cols = d_in[7];

    const int N    = in_sizes[0] / NDIM;      // 100000
    const int nnz  = in_sizes[1];             // 3200000
    const int hops = in_sizes[3] / NDIM;      // 3
    const size_t mpad = ((size_t)N + 127) & ~(size_t)127;   // 128-row tiles

    char* p = (char*)d_ws;
    ushort_t* Hb    = (ushort_t*)p; p += mpad * NDIM * 2;
    ushort_t* Hn    = (ushort_t*)p; p += mpad * NDIM * 2;
    ushort_t* Bpack = (ushort_t*)p; p += (size_t)hops * 262144 * 2;  // 512KB/hop
    float* Bc       = (float*)p; p += (size_t)hops * 256 * 4;
    int* cnt        = (int*)p; p += ((size_t)N + 256) * 4;
    int* row_start  = (int*)p; p += ((size_t)N + 256) * 4;
    int* row_cur    = (int*)p; p += ((size_t)N + 256) * 4;
    int* csum       = (int*)p; p += 512 * 4;
    int* coff       = (int*)p; p += 512 * 4;
    int* bucket_cur = (int*)p; p += 256 * 4;
    int* bstart     = (int*)p; p += 256 * 4;
    int* iflag      = (int*)p; p += 64;
    int* fflag      = (int*)p; p += 64;
    p = (char*)(((uintptr_t)p + 15) & ~(uintptr_t)15);
    int2e* edata = (int2e*)p; p += (size_t)nnz * 8;

    // int4 temp for binned edges: alias Hn (dead until first SpMM) when it fits
    int4e* tmp;
    if ((size_t)nnz * 16 <= mpad * NDIM * 2) {
        tmp = (int4e*)Hn;
    } else {
        p = (char*)(((uintptr_t)p + 15) & ~(uintptr_t)15);
        tmp = (int4e*)p; p += (size_t)nnz * 16;
    }

    (void)hipMemsetAsync(cnt, 0, (size_t)(N + 1) * sizeof(int), stream);
    if (mpad > (size_t)N) {
        (void)hipMemsetAsync(Hb + (size_t)N * NDIM, 0, (mpad - N) * NDIM * 2, stream);
    }

    k_probe<<<1, 256, 0, stream>>>((const unsigned int*)m, fflag);
    k_detect<<<1, 256, 0, stream>>>((const unsigned int*)rows, nnz, iflag);

    int nm8 = (N * NDIM) / 8;
    k_cvt_m8<<<(nm8 + 255) / 256, 256, 0, stream>>>(m, Hb, nm8, fflag);

    int nb = hops * 256;
    k_bias<<<(nb + 255) / 256, 256, 0, stream>>>(bn, bs, Bc, nb, fflag);

    int wtotal = hops << 17;
    k_wpack<<<(wtotal + 255) / 256, 256, 0, stream>>>(Wn, Ws, Bpack, wtotal, fflag);

    k_hist<<<(nnz + 255) / 256, 256, 0, stream>>>(rows, cnt, nnz, iflag);

    int nchunks = (N + 255) / 256;
    k_chunksum<<<nchunks, 256, 0, stream>>>(cnt, csum, N);
    k_scanchunks<<<1, 512, 0, stream>>>(csum, coff, nchunks);
    k_scanwrite<<<nchunks, 256, 0, stream>>>(cnt, coff, row_start, row_cur, N, nnz);

    // bucket shift: smallest sh with (N-1)>>sh < BINB
    int sh = 0;
    while (((N - 1) >> sh) >= BINB) sh++;

    k_binit<<<1, 256, 0, stream>>>(row_start, bucket_cur, bstart, N, sh);
    k_bin<<<(nnz + 4095) / 4096, 256, 0, stream>>>(rows, cols, vals, bucket_cur, tmp, nnz, sh, iflag, fflag);
    k_place<<<(BINB / 8) * PLACE_G * 8, 256, 0, stream>>>(tmp, bstart, row_cur, edata);

    if (mpad > (size_t)N) {
        (void)hipMemsetAsync(Hn + (size_t)N * NDIM, 0, (mpad - N) * NDIM * 2, stream);
    }

    int spmm_blocks = (N + 3) / 4;
    int gemm_blocks = (int)(mpad / 128);

    for (int hop = 0; hop < hops; ++hop) {
        k_spmm<<<spmm_blocks, 256, 0, stream>>>(Hb, row_start, edata, Hn, N);
        int last = (hop == hops - 1);
        void* dst = last ? d_out : (void*)Hb;
        k_gemm_mfma<<<gemm_blocks, 256, 0, stream>>>(
            Hn, Hb,
            Bpack + (size_t)hop * 262144,
            Bc + (size_t)hop * 256,
            dst, last ? 0 : 1, last ? 1 : 0, N);
    }
}

// Round 8
// 1446.205 us; speedup vs baseline: 1.0822x; 1.0019x over previous
//
#include <hip/hip_runtime.h>
#include <hip/hip_bf16.h>

typedef unsigned short ushort_t;
using bf16x8 = __attribute__((ext_vector_type(8))) __bf16;
using f32x4  = __attribute__((ext_vector_type(4))) float;
using int2e  = __attribute__((ext_vector_type(2))) int;
using int4e  = __attribute__((ext_vector_type(4))) int;
using us4e   = __attribute__((ext_vector_type(4))) unsigned short;

#define NDIM 256
#define BINB 128   // coarse buckets for two-phase scatter
#define PLACE_G 2  // blocks per bucket in phase B

__device__ __forceinline__ float bf2f(ushort_t u) {
    union { unsigned int i; float f; } x; x.i = ((unsigned int)u) << 16; return x.f;
}
// round-to-nearest-even f32 -> bf16
__device__ __forceinline__ ushort_t f2bf(float f) {
    unsigned int u = __float_as_uint(f);
    unsigned int r = (u + 0x7FFFu + ((u >> 16) & 1u)) >> 16;
    return (ushort_t)r;
}
__device__ __forceinline__ float ldf(const void* p, int i, int isbf) {
    return isbf ? bf2f(((const ushort_t*)p)[i]) : ((const float*)p)[i];
}
__device__ __forceinline__ int get_idx(const void* arr, int i, int is64) {
    if (is64) return (int)((const long long*)arr)[i];
    return ((const int*)arr)[i];
}

// ---- probe m's words: bf16 data has low-u16 bf16-exponent concentrated ----
__global__ void k_probe(const unsigned int* __restrict__ w, int* __restrict__ flag) {
    __shared__ int cnt_in;
    if (threadIdx.x == 0) cnt_in = 0;
    __syncthreads();
    int local = 0;
    for (int i = threadIdx.x; i < 4096; i += blockDim.x) {
        unsigned int e = (w[i] >> 7) & 0xFFu;
        if (e >= 110u && e <= 135u) local++;
    }
    atomicAdd(&cnt_in, local);
    __syncthreads();
    if (threadIdx.x == 0) *flag = (cnt_in >= 2048) ? 1 : 0;
}

// ---- probe index width ----
__global__ void k_detect(const unsigned int* __restrict__ rows_w, int nnz, int* __restrict__ flag) {
    __shared__ int nz;
    if (threadIdx.x == 0) nz = 0;
    __syncthreads();
    int samples = min(nnz / 2, 4096);
    for (int i = threadIdx.x; i < samples; i += blockDim.x) {
        if (rows_w[2 * i + 1] != 0u) atomicAdd(&nz, 1);
    }
    __syncthreads();
    if (threadIdx.x == 0) *flag = (nz == 0) ? 1 : 0;
}

// ---- m -> Hb (canonical bf16), 32B per thread (G13: vectorize memory-bound passes) ----
__global__ void k_cvt_m8(const void* __restrict__ src, ushort_t* __restrict__ dst, int n8,
                         const int* __restrict__ flag) {
    int i = blockIdx.x * blockDim.x + threadIdx.x;
    if (i >= n8) return;
    int isbf = *flag;
    us4e* d = reinterpret_cast<us4e*>(dst);
    if (isbf) {
        const us4e* s = reinterpret_cast<const us4e*>(src);
        d[2 * i]     = s[2 * i];
        d[2 * i + 1] = s[2 * i + 1];
    } else {
        const f32x4* s = reinterpret_cast<const f32x4*>(src);
        f32x4 a = s[2 * i];
        f32x4 b = s[2 * i + 1];
        us4e o0, o1;
        o0[0] = f2bf(a[0]); o0[1] = f2bf(a[1]); o0[2] = f2bf(a[2]); o0[3] = f2bf(a[3]);
        o1[0] = f2bf(b[0]); o1[1] = f2bf(b[1]); o1[2] = f2bf(b[2]); o1[3] = f2bf(b[3]);
        d[2 * i]     = o0;
        d[2 * i + 1] = o1;
    }
}

// ---- combined bias bn+bs -> f32 ----
__global__ void k_bias(const void* __restrict__ bn, const void* __restrict__ bs,
                       float* __restrict__ bc, int n, const int* __restrict__ flag) {
    int i = blockIdx.x * blockDim.x + threadIdx.x;
    if (i >= n) return;
    int isbf = *flag;
    bc[i] = ldf(bn, i, isbf) + ldf(bs, i, isbf);
}

// ---- weight pack into MFMA fragment order, split hi/lo bf16 ----
// Bpack layout (ushorts): [hop][kstep 0..15][p 0..31][lane 0..63][j 0..7]
//   p = ntile*2 + hilo ; frag = 512 ush (1KB) ; per-kstep chunk = 16384 ush (32KB)
__global__ void k_wpack(const void* __restrict__ Wn, const void* __restrict__ Ws,
                        ushort_t* __restrict__ bpack, int total, const int* __restrict__ flag) {
    int t = blockIdx.x * blockDim.x + threadIdx.x;
    if (t >= total) return;
    int isbf  = *flag;
    int j     = t & 7;
    int lane  = (t >> 3) & 63;
    int ntile = (t >> 9) & 15;
    int kstep = (t >> 13) & 15;
    int hop   = t >> 17;
    int k = (kstep << 5) + ((lane >> 4) << 3) + j;   // 0..511 activation k
    int n = (ntile << 4) + (lane & 15);              // 0..255 output col
    int kk = k & 255;
    float w = (k < 256) ? ldf(Wn, hop * 65536 + n * 256 + kk, isbf)
                        : ldf(Ws, hop * 65536 + n * 256 + kk, isbf);
    ushort_t hi = f2bf(w);
    float lo = w - bf2f(hi);
    int base = ((((hop << 4) + kstep) << 5) + (ntile << 1)) * 512 + (lane << 3) + j;
    bpack[base]       = hi;
    bpack[base + 512] = f2bf(lo);
}

// ---- CSR build ----
__global__ void k_hist(const void* __restrict__ rows, int* __restrict__ cnt, int nnz,
                       const int* __restrict__ flag) {
    int is64 = *flag;
    int i = blockIdx.x * blockDim.x + threadIdx.x;
    if (i < nnz) atomicAdd(&cnt[get_idx(rows, i, is64)], 1);
}

__global__ void k_chunksum(const int* __restrict__ cnt, int* __restrict__ csum, int n) {
    __shared__ int s[256];
    int i = blockIdx.x * 256 + threadIdx.x;
    int v = (i < n) ? cnt[i] : 0;
    s[threadIdx.x] = v;
    __syncthreads();
    for (int off = 128; off > 0; off >>= 1) {
        if (threadIdx.x < off) s[threadIdx.x] += s[threadIdx.x + off];
        __syncthreads();
    }
    if (threadIdx.x == 0) csum[blockIdx.x] = s[0];
}

__global__ void k_scanchunks(const int* __restrict__ csum, int* __restrict__ coff, int nchunks) {
    __shared__ int a[512], b[512];
    int t = threadIdx.x;
    int v = (t < nchunks) ? csum[t] : 0;
    a[t] = v;
    __syncthreads();
    int* src = a; int* dst = b;
    for (int off = 1; off < 512; off <<= 1) {
        dst[t] = src[t] + ((t >= off) ? src[t - off] : 0);
        __syncthreads();
        int* tmp = src; src = dst; dst = tmp;
    }
    if (t < nchunks) coff[t] = src[t] - v;   // exclusive
}

__global__ void k_scanwrite(const int* __restrict__ cnt, const int* __restrict__ coff,
                            int* __restrict__ row_start, int* __restrict__ row_cur,
                            int n, int nnz) {
    __shared__ int a[256], b[256];
    int t = threadIdx.x;
    int i = blockIdx.x * 256 + t;
    int v = (i < n) ? cnt[i] : 0;
    a[t] = v;
    __syncthreads();
    int* src = a; int* dst = b;
    for (int off = 1; off < 256; off <<= 1) {
        dst[t] = src[t] + ((t >= off) ? src[t - off] : 0);
        __syncthreads();
        int* tmp = src; src = dst; dst = tmp;
    }
    int excl = src[t] - v + coff[blockIdx.x];
    if (i < n) { row_start[i] = excl; row_cur[i] = excl; }
    if (i == n) row_start[n] = nnz;
}

// ---- bucket init ----
__global__ void k_binit(const int* __restrict__ row_start, int* __restrict__ bucket_cur,
                        int* __restrict__ bstart, int n, int sh) {
    int b = threadIdx.x;
    if (b <= BINB) {
        int idx = b << sh;
        if (idx > n) idx = n;
        int rs = row_start[idx];
        bstart[b] = rs;
        if (b < BINB) bucket_cur[b] = rs;
    }
}

// ---- phase A: bin edges into BINB coarse buckets ----
__global__ __launch_bounds__(256) void k_bin(
        const void* __restrict__ rows, const void* __restrict__ cols,
        const void* __restrict__ vals, int* __restrict__ bucket_cur,
        int4e* __restrict__ tmp, int nnz, int sh,
        const int* __restrict__ iflag, const int* __restrict__ fflag) {
    __shared__ int cntL[BINB];
    __shared__ int curL[BINB];
    int is64 = *iflag, isbf = *fflag;
    int tid = threadIdx.x;
    int base = blockIdx.x * 4096;
    if (tid < BINB) cntL[tid] = 0;
    __syncthreads();
    int r[16], b[16];
    #pragma unroll
    for (int j = 0; j < 16; ++j) {
        int idx = base + (j << 8) + tid;
        if (idx < nnz) {
            r[j] = get_idx(rows, idx, is64);
            b[j] = r[j] >> sh;
            atomicAdd(&cntL[b[j]], 1);
        } else b[j] = -1;
    }
    __syncthreads();
    if (tid < BINB) curL[tid] = atomicAdd(&bucket_cur[tid], cntL[tid]);
    __syncthreads();
    #pragma unroll
    for (int j = 0; j < 16; ++j) {
        int idx = base + (j << 8) + tid;
        if (idx < nnz) {
            int c = get_idx(cols, idx, is64);
            float v = ldf(vals, idx, isbf);
            int p = atomicAdd(&curL[b[j]], 1);
            int4e ed; ed[0] = r[j]; ed[1] = c; ed[2] = __float_as_int(v); ed[3] = 0;
            tmp[p] = ed;   // normal store: tmp is re-read immediately by k_place (keep in L2)
        }
    }
}

// ---- phase B: exact CSR placement within one bucket's L2-resident window ----
__global__ __launch_bounds__(256) void k_place(
        const int4e* __restrict__ tmp, const int* __restrict__ bstart,
        int* __restrict__ row_cur, int2e* __restrict__ edata) {
    int blk = blockIdx.x;
    int xcd = blk & 7;
    int q   = blk >> 3;
    int g   = q & (PLACE_G - 1);
    int bq  = q >> 1;                 // log2(PLACE_G) = 1
    int b   = (bq << 3) | xcd;
    int e0 = bstart[b], e1 = bstart[b + 1];
    int len = e1 - e0;
    if (len <= 0) return;
    int sub = (len + PLACE_G - 1) / PLACE_G;
    int es = e0 + g * sub;
    int ee = min(es + sub, e1);
    for (int e = es + threadIdx.x; e < ee; e += 256) {
        int4e ed = tmp[e];
        int p = atomicAdd(&row_cur[ed[0]], 1);
        int2e o; o[0] = ed[1]; o[1] = ed[2];
        edata[p] = o;
    }
}

// ---- SpMM: one wave per row, fp32 accumulate, bf16 in/out ----
// BW-bound on the L2-miss path (~3.9 TB/s plateau, FETCH 768 MB): 2 gather
// chains suffice; nt hints keep streaming edata/Hn out of L2 for the Hb gather.
__global__ void k_spmm(const ushort_t* __restrict__ hb, const int* __restrict__ row_start,
                       const int2e* __restrict__ edata, ushort_t* __restrict__ hn, int n) {
    int wid = (blockIdx.x * blockDim.x + threadIdx.x) >> 6;
    if (wid >= n) return;
    wid = __builtin_amdgcn_readfirstlane(wid);
    int lane = threadIdx.x & 63;
    int e0 = row_start[wid];
    int e1 = row_start[wid + 1];
    float a0 = 0.f, a1 = 0.f, a2 = 0.f, a3 = 0.f;
    float c0 = 0.f, c1 = 0.f, c2 = 0.f, c3 = 0.f;
    int off = lane * 4;
    int e = e0;
    if ((e & 1) && e < e1) {           // align to 16B edata pairs
        int2e ed = __builtin_nontemporal_load(&edata[e]);
        float v = __int_as_float(ed[1]);
        ushort4 h = *reinterpret_cast<const ushort4*>(hb + (((long)ed[0]) << 8) + off);
        a0 += bf2f(h.x) * v; a1 += bf2f(h.y) * v;
        a2 += bf2f(h.z) * v; a3 += bf2f(h.w) * v;
        ++e;
    }
    for (; e + 1 < e1; e += 2) {
        int4e p0 = __builtin_nontemporal_load(reinterpret_cast<const int4e*>(&edata[e]));
        float v0 = __int_as_float(p0[1]);
        float v1 = __int_as_float(p0[3]);
        ushort4 h0 = *reinterpret_cast<const ushort4*>(hb + (((long)p0[0]) << 8) + off);
        ushort4 h1 = *reinterpret_cast<const ushort4*>(hb + (((long)p0[2]) << 8) + off);
        a0 += bf2f(h0.x) * v0; a1 += bf2f(h0.y) * v0;
        a2 += bf2f(h0.z) * v0; a3 += bf2f(h0.w) * v0;
        c0 += bf2f(h1.x) * v1; c1 += bf2f(h1.y) * v1;
        c2 += bf2f(h1.z) * v1; c3 += bf2f(h1.w) * v1;
    }
    if (e < e1) {
        int2e ed = __builtin_nontemporal_load(&edata[e]);
        float v = __int_as_float(ed[1]);
        ushort4 h = *reinterpret_cast<const ushort4*>(hb + (((long)ed[0]) << 8) + off);
        a0 += bf2f(h.x) * v; a1 += bf2f(h.y) * v;
        a2 += bf2f(h.z) * v; a3 += bf2f(h.w) * v;
    }
    a0 += c0; a1 += c1; a2 += c2; a3 += c3;
    us4e o;
    o[0] = f2bf(a0); o[1] = f2bf(a1); o[2] = f2bf(a2); o[3] = f2bf(a3);
    __builtin_nontemporal_store(o, reinterpret_cast<us4e*>(hn + (((long)wid) << 8) + off));
}

// ---- stage one 32KB Bpack k-chunk into LDS via async global->LDS, 16B/lane ----
__device__ __forceinline__ void stage32k(const ushort_t* __restrict__ src, ushort_t* dstlds, int tid) {
    const char* s = (const char*)src;
    char* d = (char*)dstlds;
    #pragma unroll
    for (int i = 0; i < 8; ++i) {
        int off = i * 4096 + tid * 16;
        __builtin_amdgcn_global_load_lds(
            (const __attribute__((address_space(1))) unsigned int*)(s + off),
            (__attribute__((address_space(3))) unsigned int*)(d + off),
            16, 0, 0);
    }
}

// ---- MFMA GEMM: out[r][n] = act( sum_k Hn[r][k]*WtN[k][n] + Hb[r][k]*WtS[k][n] + bc[n] )
// 2-phase schedule with STATIC register double-buffering: even/odd K-step bodies
// are macro-expanded so afA/afB and lds[0]/lds[1] are referenced textually —
// no runtime-selected pointer into a register array (rule #20: that demotes the
// fragment arrays to scratch). A-loads (HBM, long pole) issued first after the
// barrier; B-stage (L2-resident) second; both drain at the NEXT barrier.
__global__ __launch_bounds__(256, 2) void k_gemm_mfma(
        const ushort_t* __restrict__ hn, const ushort_t* __restrict__ hb,
        const ushort_t* __restrict__ bpack, const float* __restrict__ bc,
        void* __restrict__ dst, int applyElu, int writeF32, int nvalid) {
    __shared__ __align__(16) ushort_t lds[2][16384];   // 2 x 32KB
    int tid  = threadIdx.x;
    int wave = tid >> 6, lane = tid & 63;
    int wm = wave >> 1, wn = wave & 1;
    long rowbase = blockIdx.x * 128 + wm * 64;
    int lr = lane & 15;            // A-row / B-col / D-col within fragment
    int lk = (lane >> 4) << 3;     // k sub-offset 0,8,16,24

    f32x4 acc[4][8];
    #pragma unroll
    for (int mf = 0; mf < 4; ++mf)
        #pragma unroll
        for (int nf = 0; nf < 8; ++nf) acc[mf][nf] = (f32x4){0.f, 0.f, 0.f, 0.f};

    bf16x8 afA0, afA1, afA2, afA3;   // named scalars: cannot be scratch-demoted
    bf16x8 afB0, afB1, afB2, afB3;

    // prologue: stage ks=0 B-chunk, load ks=0 A-frags (asrc=hn, kcol=lk)
    stage32k(bpack, &lds[0][0], tid);
    afA0 = *(const bf16x8*)(hn + ((rowbase +  0 + lr) << 8) + lk);
    afA1 = *(const bf16x8*)(hn + ((rowbase + 16 + lr) << 8) + lk);
    afA2 = *(const bf16x8*)(hn + ((rowbase + 32 + lr) << 8) + lk);
    afA3 = *(const bf16x8*)(hn + ((rowbase + 48 + lr) << 8) + lk);

#define LOADA(A0, A1, A2, A3, KSN)                                             \
    {                                                                          \
        const ushort_t* asrc = ((KSN) < 8) ? hn : hb;                          \
        int kcol = (((KSN) & 7) << 5) + lk;                                    \
        A0 = *(const bf16x8*)(asrc + ((rowbase +  0 + lr) << 8) + kcol);       \
        A1 = *(const bf16x8*)(asrc + ((rowbase + 16 + lr) << 8) + kcol);       \
        A2 = *(const bf16x8*)(asrc + ((rowbase + 32 + lr) << 8) + kcol);       \
        A3 = *(const bf16x8*)(asrc + ((rowbase + 48 + lr) << 8) + kcol);       \
    }

#define COMPUTE(BUF, A0, A1, A2, A3)                                           \
    {                                                                          \
        const ushort_t* bb = &lds[BUF][0];                                     \
        _Pragma("unroll")                                                      \
        for (int nf = 0; nf < 8; ++nf) {                                       \
            const ushort_t* fp = bb + ((((wn << 3) + nf) << 1) << 9) + (lane << 3); \
            bf16x8 bhi = *(const bf16x8*)(fp);                                 \
            bf16x8 blo = *(const bf16x8*)(fp + 512);                           \
            acc[0][nf] = __builtin_amdgcn_mfma_f32_16x16x32_bf16(A0, bhi, acc[0][nf], 0, 0, 0); \
            acc[0][nf] = __builtin_amdgcn_mfma_f32_16x16x32_bf16(A0, blo, acc[0][nf], 0, 0, 0); \
            acc[1][nf] = __builtin_amdgcn_mfma_f32_16x16x32_bf16(A1, bhi, acc[1][nf], 0, 0, 0); \
            acc[1][nf] = __builtin_amdgcn_mfma_f32_16x16x32_bf16(A1, blo, acc[1][nf], 0, 0, 0); \
            acc[2][nf] = __builtin_amdgcn_mfma_f32_16x16x32_bf16(A2, bhi, acc[2][nf], 0, 0, 0); \
            acc[2][nf] = __builtin_amdgcn_mfma_f32_16x16x32_bf16(A2, blo, acc[2][nf], 0, 0, 0); \
            acc[3][nf] = __builtin_amdgcn_mfma_f32_16x16x32_bf16(A3, bhi, acc[3][nf], 0, 0, 0); \
            acc[3][nf] = __builtin_amdgcn_mfma_f32_16x16x32_bf16(A3, blo, acc[3][nf], 0, 0, 0); \
        }                                                                      \
    }

    #pragma unroll 1
    for (int kp = 0; kp < 8; ++kp) {
        int ks0 = kp << 1;           // even step: buf 0, compute afA, prefetch afB
        __syncthreads();             // drains stage(ks0)+A(ks0) issued last step
        LOADA(afB0, afB1, afB2, afB3, ks0 + 1)
        stage32k(bpack + (ks0 + 1) * 16384, &lds[1][0], tid);
        COMPUTE(0, afA0, afA1, afA2, afA3)

        __syncthreads();             // drains stage(ks0+1)+A(ks0+1)
        if (kp < 7) {                // odd step: buf 1, compute afB, prefetch afA
            LOADA(afA0, afA1, afA2, afA3, ks0 + 2)
            stage32k(bpack + (ks0 + 2) * 16384, &lds[0][0], tid);
        }
        COMPUTE(1, afB0, afB1, afB2, afB3)
    }
#undef LOADA
#undef COMPUTE

    // epilogue: D frag layout col=lane&15, row=(lane>>4)*4+reg (m89-verified)
    int colb = wn << 7;
    float bcv[8];
    #pragma unroll
    for (int nf = 0; nf < 8; ++nf) bcv[nf] = bc[colb + (nf << 4) + lr];
    int rsub = (lane >> 4) << 2;
    #pragma unroll
    for (int mf = 0; mf < 4; ++mf) {
        #pragma unroll
        for (int r = 0; r < 4; ++r) {
            long row = rowbase + mf * 16 + rsub + r;
            if (row < nvalid) {
                #pragma unroll
                for (int nf = 0; nf < 8; ++nf) {
                    float v = acc[mf][nf][r] + bcv[nf];
                    if (applyElu) v = (v > 0.f) ? v : expm1f(v);
                    int col = colb + (nf << 4) + lr;
                    if (writeF32) ((float*)dst)[(row << 8) + col] = v;
                    else          ((ushort_t*)dst)[(row << 8) + col] = f2bf(v);
                }
            }
        }
    }
}

extern "C" void kernel_launch(void* const* d_in, const int* in_sizes, int n_in,
                              void* d_out, int out_size, void* d_ws, size_t ws_size,
                              hipStream_t stream) {
    const void* m    = d_in[0];
    const void* vals = d_in[1];
    const void* Wn   = d_in[2];
    const void* bn   = d_in[3];
    const void* Ws   = d_in[4];
    const void* bs   = d_in[5];
    const void* rows = d_in[6];
    const void* cols = d_in[7];

    const int N    = in_sizes[0] / NDIM;      // 100000
    const int nnz  = in_sizes[1];             // 3200000
    const int hops = in_sizes[3] / NDIM;      // 3
    const size_t mpad = ((size_t)N + 127) & ~(size_t)127;   // 128-row tiles

    char* p = (char*)d_ws;
    ushort_t* Hb    = (ushort_t*)p; p += mpad * NDIM * 2;
    ushort_t* Hn    = (ushort_t*)p; p += mpad * NDIM * 2;
    ushort_t* Bpack = (ushort_t*)p; p += (size_t)hops * 262144 * 2;  // 512KB/hop
    float* Bc       = (float*)p; p += (size_t)hops * 256 * 4;
    int* cnt        = (int*)p; p += ((size_t)N + 256) * 4;
    int* row_start  = (int*)p; p += ((size_t)N + 256) * 4;
    int* row_cur    = (int*)p; p += ((size_t)N + 256) * 4;
    int* csum       = (int*)p; p += 512 * 4;
    int* coff       = (int*)p; p += 512 * 4;
    int* bucket_cur = (int*)p; p += 256 * 4;
    int* bstart     = (int*)p; p += 256 * 4;
    int* iflag      = (int*)p; p += 64;
    int* fflag      = (int*)p; p += 64;
    p = (char*)(((uintptr_t)p + 15) & ~(uintptr_t)15);
    int2e* edata = (int2e*)p; p += (size_t)nnz * 8;

    // int4 temp for binned edges: alias Hn (dead until first SpMM) when it fits
    int4e* tmp;
    if ((size_t)nnz * 16 <= mpad * NDIM * 2) {
        tmp = (int4e*)Hn;
    } else {
        p = (char*)(((uintptr_t)p + 15) & ~(uintptr_t)15);
        tmp = (int4e*)p; p += (size_t)nnz * 16;
    }

    (void)hipMemsetAsync(cnt, 0, (size_t)(N + 1) * sizeof(int), stream);
    if (mpad > (size_t)N) {
        (void)hipMemsetAsync(Hb + (size_t)N * NDIM, 0, (mpad - N) * NDIM * 2, stream);
    }

    k_probe<<<1, 256, 0, stream>>>((const unsigned int*)m, fflag);
    k_detect<<<1, 256, 0, stream>>>((const unsigned int*)rows, nnz, iflag);

    int nm8 = (N * NDIM) / 8;
    k_cvt_m8<<<(nm8 + 255) / 256, 256, 0, stream>>>(m, Hb, nm8, fflag);

    int nb = hops * 256;
    k_bias<<<(nb + 255) / 256, 256, 0, stream>>>(bn, bs, Bc, nb, fflag);

    int wtotal = hops << 17;
    k_wpack<<<(wtotal + 255) / 256, 256, 0, stream>>>(Wn, Ws, Bpack, wtotal, fflag);

    k_hist<<<(nnz + 255) / 256, 256, 0, stream>>>(rows, cnt, nnz, iflag);

    int nchunks = (N + 255) / 256;
    k_chunksum<<<nchunks, 256, 0, stream>>>(cnt, csum, N);
    k_scanchunks<<<1, 512, 0, stream>>>(csum, coff, nchunks);
    k_scanwrite<<<nchunks, 256, 0, stream>>>(cnt, coff, row_start, row_cur, N, nnz);

    // bucket shift: smallest sh with (N-1)>>sh < BINB
    int sh = 0;
    while (((N - 1) >> sh) >= BINB) sh++;

    k_binit<<<1, 256, 0, stream>>>(row_start, bucket_cur, bstart, N, sh);
    k_bin<<<(nnz + 4095) / 4096, 256, 0, stream>>>(rows, cols, vals, bucket_cur, tmp, nnz, sh, iflag, fflag);
    k_place<<<(BINB / 8) * PLACE_G * 8, 256, 0, stream>>>(tmp, bstart, row_cur, edata);

    if (mpad > (size_t)N) {
        (void)hipMemsetAsync(Hn + (size_t)N * NDIM, 0, (mpad - N) * NDIM * 2, stream);
    }

    int spmm_blocks = (N + 3) / 4;
    int gemm_blocks = (int)(mpad / 128);

    for (int hop = 0; hop < hops; ++hop) {
        k_spmm<<<spmm_blocks, 256, 0, stream>>>(Hb, row_start, edata, Hn, N);
        int last = (hop == hops - 1);
        void* dst = last ? d_out : (void*)Hb;
        k_gemm_mfma<<<gemm_blocks, 256, 0, stream>>>(
            Hn, Hb,
            Bpack + (size_t)hop * 262144,
            Bc + (size_t)hop * 256,
            dst, last ? 0 : 1, last ? 1 : 0, N);
    }
}